// Round 8
// baseline (522.273 us; speedup 1.0000x reference)
//
#include <hip/hip_runtime.h>
#include <stdint.h>

typedef __attribute__((ext_vector_type(8))) short short8;
typedef __attribute__((ext_vector_type(4))) float f32x4;

constexpr int T_ = 4;
constexpr int BNTOT = 32768; // B*N

// f32 -> bf16 (RNE)
__device__ __forceinline__ uint32_t bf1(float f) {
    uint32_t x = __builtin_bit_cast(uint32_t, f);
    return (x + 0x7FFFu + ((x >> 16) & 1u)) >> 16;
}
__device__ __forceinline__ uint32_t pk(float lo, float hi) {
    return bf1(lo) | (bf1(hi) << 16);
}

// 8 u8 {0,1} -> 8 bf16 {0,1.0}: v_perm spreads bytes to u16 lanes, *0x3F80.
__device__ __forceinline__ short8 expand8(uint2 r) {
    uint4 o;
    o.x = __builtin_amdgcn_perm(0u, r.x, 0x0C010C00u) * 0x3F80u;
    o.y = __builtin_amdgcn_perm(0u, r.x, 0x0C030C02u) * 0x3F80u;
    o.z = __builtin_amdgcn_perm(0u, r.y, 0x0C010C00u) * 0x3F80u;
    o.w = __builtin_amdgcn_perm(0u, r.y, 0x0C030C02u) * 0x3F80u;
    return __builtin_bit_cast(short8, o);
}

// Fused bf16-MFMA GEMM (C = A @ W^T) + multi-step LIF over T=4.
// A: MODE 0: row-major f32 x [T][BN][K] (cvt folded in);
//    MODE 1/2: tiled u8 [T][BN/16][K/8][16][8].
// W: f32 [NOUT][K], staged to LDS in 32KB halves (bf16, XOR-swizzled).
// Out: MODE 0/1: tiled u8 [T][BN/16][NOUT/8][16][8] (coalesced uint4 stores);
//      MODE 2: f32 [T][BN][NOUT] (float4 stores via LDS repack).
// Block: 4 waves; wave w owns rows [row0+16w,+16) for ALL t; t-scan is
// thread-local. K-loop barrier-free; A prefetched 2 steps ahead (4 reg sets).
template <int MODE, int K, int NOUT>
__global__ __launch_bounds__(256, 4)
void lif_mfma(const void* __restrict__ Av,
              const float* __restrict__ W,
              void* __restrict__ Out)
{
    constexpr int NS = K / 32;                 // K-steps
    constexpr int PANEL = (NS > 8) ? 8 : NS;   // steps per staged B panel
    constexpr int HALVES = NS / PANEL;
    constexpr int NCOLT = NOUT / 64;
    __shared__ __align__(16) char smem[32768]; // B panel; epilogue aliases it

    const int tid = threadIdx.x;
    const int l   = tid & 63;
    const int w   = tid >> 6;

    // XCD-bijective swizzle: xcd owns contiguous row-tile chunk, cols fastest.
    const int id  = blockIdx.x;
    const int xcd = id & 7;
    const int j_  = id >> 3;
    const int row0 = (xcd * 64 + j_ / NCOLT) * 64;
    const int col0 = (j_ % NCOLT) * 64;

    const char* bbase = smem + (l & 15) * 64 + (((l >> 4) ^ ((l >> 1) & 3)) * 16);

    // stage one 32KB B half-panel: 64 cols x PANEL*4 granules, 8 units/thread
    auto stageB = [&](int hf) {
#pragma unroll
        for (int i = 0; i < 8; ++i) {
            const int idx = i * 256 + tid;
            const int c = idx >> 5, kgl = idx & 31;
            const float* wp = W + (size_t)(col0 + c) * K + (hf * PANEL * 4 + kgl) * 8;
            const float4 f0 = *(const float4*)wp;
            const float4 f1 = *(const float4*)(wp + 4);
            uint4 o;
            o.x = pk(f0.x, f0.y); o.y = pk(f0.z, f0.w);
            o.z = pk(f1.x, f1.y); o.w = pk(f1.z, f1.w);
            *(uint4*)(smem + ((c >> 4) * PANEL + (kgl >> 2)) * 1024 + (c & 15) * 64 +
                      (((kgl & 3) ^ ((c >> 1) & 3)) * 16)) = o;
        }
    };

    f32x4 acc[T_][4];
#pragma unroll
    for (int t = 0; t < T_; ++t)
#pragma unroll
        for (int n = 0; n < 4; ++n) acc[t][n] = (f32x4)0.f;

    // A bases
    const uint8_t* au_base = (const uint8_t*)Av +
        (((size_t)((row0 >> 4) + w)) * (K / 8) + (l >> 4)) * 128 + (l & 15) * 8;
    const float* ax_base = (const float*)Av +
        ((size_t)(row0 + w * 16 + (l & 15))) * K + (l >> 4) * 8;

    auto loadAu = [&](int s, uint2 a[T_]) {
#pragma unroll
        for (int t = 0; t < T_; ++t)
            a[t] = *(const uint2*)(au_base +
                     ((size_t)t * (BNTOT / 16) * (K / 8) + s * 4) * 128);
    };
    auto loadAx = [&](int s, short8 a[T_]) {
#pragma unroll
        for (int t = 0; t < T_; ++t) {
            const float* p = ax_base + (size_t)t * BNTOT * K + s * 32;
            const float4 u = *(const float4*)p;
            const float4 v2 = *(const float4*)(p + 4);
            uint4 o;
            o.x = pk(u.x, u.y);  o.y = pk(u.z, u.w);
            o.z = pk(v2.x, v2.y); o.w = pk(v2.z, v2.w);
            a[t] = __builtin_bit_cast(short8, o);
        }
    };
    auto stepF = [&](const short8 a[T_], int sl) {
        short8 bfr[4];
#pragma unroll
        for (int n = 0; n < 4; ++n)
            bfr[n] = *(const short8*)(bbase + (n * PANEL + sl) * 1024);
#pragma unroll
        for (int t = 0; t < T_; ++t)
#pragma unroll
            for (int n = 0; n < 4; ++n)
                acc[t][n] = __builtin_amdgcn_mfma_f32_16x16x32_bf16(
                    a[t], bfr[n], acc[t][n], 0, 0, 0);
    };
    auto stepU = [&](const uint2 a[T_], int sl) {
        short8 bfr[4];
#pragma unroll
        for (int n = 0; n < 4; ++n)
            bfr[n] = *(const short8*)(bbase + (n * PANEL + sl) * 1024);
#pragma unroll
        for (int t = 0; t < T_; ++t) {
            const short8 af = expand8(a[t]);
#pragma unroll
            for (int n = 0; n < 4; ++n)
                acc[t][n] = __builtin_amdgcn_mfma_f32_16x16x32_bf16(
                    af, bfr[n], acc[t][n], 0, 0, 0);
        }
    };

    stageB(0);
    __syncthreads();

    if constexpr (MODE == 0) {
        // K=256: single panel; f32 source with fold-in cvt; depth-1, 2 sets
        short8 aA[T_], aB[T_];
        loadAx(0, aA);
        for (int s = 0; s < NS; s += 2) {
            loadAx(s + 1 < NS ? s + 1 : 0, aB);
            stepF(aA, s);
            loadAx(s + 2 < NS ? s + 2 : 0, aA);
            stepF(aB, s + 1);
        }
    } else {
        // u8 source; depth-2 pipeline with 4 named sets; panel halves
        uint2 aA[T_], aB[T_], aC[T_], aD[T_];
        loadAu(0, aA);
        loadAu(1, aB);
        for (int hf = 0; hf < HALVES; ++hf) {
            if (hf) { __syncthreads(); stageB(hf); __syncthreads(); }
            const int base = hf * PANEL;
#pragma unroll
            for (int ss = 0; ss < PANEL; ss += 4) {
                const int s = base + ss;
                loadAu(s + 2 < NS ? s + 2 : 0, aC); stepU(aA, ss + 0);
                loadAu(s + 3 < NS ? s + 3 : 0, aD); stepU(aB, ss + 1);
                loadAu(s + 4 < NS ? s + 4 : 0, aA); stepU(aC, ss + 2);
                loadAu(s + 5 < NS ? s + 5 : 0, aB); stepU(aD, ss + 3);
            }
        }
    }

    __syncthreads();   // B panel dead; epilogue LDS aliases it

    // ---- epilogue: thread-local LIF t-scan + LDS repack + coalesced stores ----
    // C/D map: col = l&15 (+n*16), row = (l>>4)*4 + j (+ w*16)
    if constexpr (MODE == 2) {
        float* fl = (float*)smem;              // [64][68] f32, padded
        float v[4][4];
#pragma unroll
        for (int n = 0; n < 4; ++n)
#pragma unroll
            for (int j = 0; j < 4; ++j) v[n][j] = 0.f;
#pragma unroll
        for (int t = 0; t < T_; ++t) {
#pragma unroll
            for (int n = 0; n < 4; ++n)
#pragma unroll
                for (int j = 0; j < 4; ++j) {
                    v[n][j] = 0.5f * (v[n][j] + acc[t][n][j]);
                    const bool sp = (v[n][j] >= 1.f);
                    if (sp) v[n][j] = 0.f;
                    fl[(w * 16 + (l >> 4) * 4 + j) * 68 + n * 16 + (l & 15)] =
                        sp ? 1.f : 0.f;
                }
            __syncthreads();
            const int r  = tid >> 2;
            const int cb = (tid & 3) * 16;
            float* op = (float*)Out +
                ((size_t)(t * BNTOT + row0 + r)) * NOUT + col0 + cb;
#pragma unroll
            for (int k = 0; k < 4; ++k)
                *(float4*)(op + k * 4) = *(const float4*)&fl[r * 68 + cb + k * 4];
            __syncthreads();
        }
    } else {
        char* el = smem;   // [4t][4w][8cg][16r][8c] = 16KB
        float v[4][4];
#pragma unroll
        for (int n = 0; n < 4; ++n)
#pragma unroll
            for (int j = 0; j < 4; ++j) v[n][j] = 0.f;
#pragma unroll
        for (int t = 0; t < T_; ++t)
#pragma unroll
            for (int n = 0; n < 4; ++n)
#pragma unroll
                for (int j = 0; j < 4; ++j) {
                    v[n][j] = 0.5f * (v[n][j] + acc[t][n][j]);
                    const bool sp = (v[n][j] >= 1.f);
                    if (sp) v[n][j] = 0.f;
                    el[t * 4096 + w * 1024 + (n * 2 + ((l & 15) >> 3)) * 128 +
                       ((l >> 4) * 4 + j) * 8 + (l & 7)] =
                        (MODE == 0) ? (sp ? 1 : 0) : (sp ? 0 : 0xFF);
                }
        __syncthreads();
        // phase B: 64 consecutive bytes per thread -> 4 coalesced uint4 stores
        const int lin = tid * 64;
        const int t  = lin >> 12;
        const int w2 = (lin >> 10) & 3;
        const int cg = (lin >> 7) & 7;
        const size_t gb = ((size_t)(t * (BNTOT / 16) + (row0 >> 4) + w2) *
                          (NOUT / 8) + (col0 >> 3) + cg) * 128 + (lin & 127);
#pragma unroll
        for (int k = 0; k < 4; ++k) {
            uint4 m = *(const uint4*)(el + lin + k * 16);
            if constexpr (MODE == 1) {
                const uint4 h = *(const uint4*)((const uint8_t*)Av + gb + k * 16);
                m.x &= h.x; m.y &= h.y; m.z &= h.z; m.w &= h.w;
            }
            *(uint4*)((uint8_t*)Out + gb + k * 16) = m;
        }
    }
}

extern "C" void kernel_launch(void* const* d_in, const int* in_sizes, int n_in,
                              void* d_out, int out_size, void* d_ws, size_t ws_size,
                              hipStream_t stream)
{
    const float* x     = (const float*)d_in[0];  // [4,32,1024,256]
    const float* w_in  = (const float*)d_in[1];  // [512,256]
    const float* w_h   = (const float*)d_in[2];  // [2,512,512]
    const float* w_out = (const float*)d_in[3];  // [256,512]

    // hA u8 tiled = d_ws[0:67.1MB), hB u8 tiled = d_ws[67.1:134.2MB)
    uint8_t* hA  = (uint8_t*)d_ws;
    uint8_t* hB  = hA + (size_t)T_ * BNTOT * 512;
    float*   out = (float*)d_out;

    lif_mfma<0, 256, 512><<<4096, 256, 0, stream>>>(x, w_in, hA);
    lif_mfma<1, 512, 512><<<4096, 256, 0, stream>>>(hA, w_h, hB);
    lif_mfma<1, 512, 512><<<4096, 256, 0, stream>>>(hB, w_h + 512 * 512, hA);
    lif_mfma<2, 512, 256><<<2048, 256, 0, stream>>>(hA, w_out, out);
}

// Round 9
// 419.356 us; speedup vs baseline: 1.2454x; 1.2454x over previous
//
#include <hip/hip_runtime.h>
#include <stdint.h>

typedef __attribute__((ext_vector_type(8))) short short8;
typedef __attribute__((ext_vector_type(4))) float f32x4;

constexpr int T_ = 4;
constexpr int BNTOT = 32768; // B*N

// f32 -> bf16 (RNE)
__device__ __forceinline__ uint32_t bf1(float f) {
    uint32_t x = __builtin_bit_cast(uint32_t, f);
    return (x + 0x7FFFu + ((x >> 16) & 1u)) >> 16;
}
__device__ __forceinline__ uint32_t pk(float lo, float hi) {
    return bf1(lo) | (bf1(hi) << 16);
}

// 8 u8 {0,1} -> 8 bf16 {0,1.0}: v_perm spreads bytes to u16 lanes, *0x3F80.
__device__ __forceinline__ short8 expand8(uint2 r) {
    uint4 o;
    o.x = __builtin_amdgcn_perm(0u, r.x, 0x0C010C00u) * 0x3F80u;
    o.y = __builtin_amdgcn_perm(0u, r.x, 0x0C030C02u) * 0x3F80u;
    o.z = __builtin_amdgcn_perm(0u, r.y, 0x0C010C00u) * 0x3F80u;
    o.w = __builtin_amdgcn_perm(0u, r.y, 0x0C030C02u) * 0x3F80u;
    return __builtin_bit_cast(short8, o);
}

// x [T*BN][256] f32 -> MFMA-fragment-tiled bf16 [T*BN/16][32][16][8]
__global__ __launch_bounds__(256)
void cvt_tiled(const float* __restrict__ in, ushort* __restrict__ out) {
    const int g  = blockIdx.x * 256 + threadIdx.x;
    const int kg = g & 31;
    const int r  = (g >> 5) & 15;
    const int bt = g >> 9;
    const float* src = in + ((size_t)(bt * 16 + r)) * 256 + kg * 8;
    const float4 a = *(const float4*)src;
    const float4 b = *(const float4*)(src + 4);
    uint4 o;
    o.x = pk(a.x, a.y); o.y = pk(a.z, a.w);
    o.z = pk(b.x, b.y); o.w = pk(b.z, b.w);
    *(uint4*)(out + ((size_t)(bt * 32 + kg)) * 128 + r * 8) = o;
}

// Fused bf16-MFMA GEMM (C = A @ W^T) + multi-step LIF over T=4.
// A: MODE 0: tiled bf16 [T][BN/16][K/8][16][8]; MODE 1/2: tiled u8 (same geom).
// W: f32 [NOUT][K], staged ONCE per block to LDS (full-K panel, XOR-swizzled).
// Out: MODE 0/1: tiled u8 [T][BN/16][NOUT/8][16][8] (coalesced uint4 stores);
//      MODE 2: f32 [T][BN][NOUT] (float4 stores via LDS repack).
// Block: 4 waves; wave w owns rows [row0+16w,+16) for ALL t (thread-local
// t-scan). K-loop barrier-free; A prefetch ring DEPTH sets (static unroll).
// __launch_bounds__(256,2): keep full register budget (r8 lesson: 4 waves/EU
// strangles the pipeline -> MfmaUtil 7%).
template <int MODE, int K, int NOUT>
__global__ __launch_bounds__(256, 2)
void lif_mfma(const void* __restrict__ Av,
              const float* __restrict__ W,
              void* __restrict__ Out)
{
    constexpr int NS = K / 32;      // K-steps
    constexpr int KG = K / 8;       // k-granules
    constexpr int NCOLT = NOUT / 64;
    __shared__ __align__(16) char smem[NS * 4096]; // B panel; epilogue aliases

    const int tid = threadIdx.x;
    const int l   = tid & 63;
    const int w   = tid >> 6;

    // XCD-bijective swizzle: xcd owns contiguous row-tile chunk, cols fastest.
    const int id  = blockIdx.x;
    const int xcd = id & 7;
    const int j_  = id >> 3;
    const int row0 = (xcd * 64 + j_ / NCOLT) * 64;
    const int col0 = (j_ % NCOLT) * 64;

    // ---- stage B col-panel (64 x K) f32 -> bf16 frag-tiled, XOR-swizzled ----
    {
        constexpr int ITERS = 64 * KG / 256;
#pragma unroll
        for (int i = 0; i < ITERS; ++i) {
            const int idx = i * 256 + tid;
            const int c   = idx / KG;
            const int kg  = idx % KG;
            const float* wp = W + (size_t)(col0 + c) * K + kg * 8;
            const float4 f0 = *(const float4*)wp;
            const float4 f1 = *(const float4*)(wp + 4);
            uint4 o;
            o.x = pk(f0.x, f0.y); o.y = pk(f0.z, f0.w);
            o.z = pk(f1.x, f1.y); o.w = pk(f1.z, f1.w);
            *(uint4*)(smem + ((c >> 4) * NS + (kg >> 2)) * 1024 + (c & 15) * 64 +
                      (((kg & 3) ^ ((c >> 1) & 3)) * 16)) = o;
        }
    }
    __syncthreads();

    const char* bbase = smem + (l & 15) * 64 + (((l >> 4) ^ ((l >> 1) & 3)) * 16);
    const int rb = (row0 >> 4) + w;

    f32x4 acc[T_][4];
#pragma unroll
    for (int t = 0; t < T_; ++t)
#pragma unroll
        for (int n = 0; n < 4; ++n) acc[t][n] = (f32x4)0.f;

    size_t aunit[T_];
#pragma unroll
    for (int t = 0; t < T_; ++t)
        aunit[t] = ((size_t)(t * (BNTOT / 16) + rb)) * KG + (l >> 4);

    auto loadAb = [&](int s, short8* a) {
#pragma unroll
        for (int t = 0; t < T_; ++t)
            a[t] = *(const short8*)((const ushort*)Av +
                     (aunit[t] + s * 4) * 128 + (l & 15) * 8);
    };
    auto loadAu = [&](int s, uint2* a) {
#pragma unroll
        for (int t = 0; t < T_; ++t)
            a[t] = *(const uint2*)((const uint8_t*)Av +
                     (aunit[t] + s * 4) * 128 + (l & 15) * 8);
    };
    auto stepB = [&](const short8* a, int s) {
        short8 bfr[4];
#pragma unroll
        for (int n = 0; n < 4; ++n)
            bfr[n] = *(const short8*)(bbase + (n * NS + s) * 1024);
#pragma unroll
        for (int t = 0; t < T_; ++t)
#pragma unroll
            for (int n = 0; n < 4; ++n)
                acc[t][n] = __builtin_amdgcn_mfma_f32_16x16x32_bf16(
                    a[t], bfr[n], acc[t][n], 0, 0, 0);
    };
    auto stepU = [&](const uint2* a, int s) {
        short8 bfr[4];
#pragma unroll
        for (int n = 0; n < 4; ++n)
            bfr[n] = *(const short8*)(bbase + (n * NS + s) * 1024);
#pragma unroll
        for (int t = 0; t < T_; ++t) {
            const short8 af = expand8(a[t]);
#pragma unroll
            for (int n = 0; n < 4; ++n)
                acc[t][n] = __builtin_amdgcn_mfma_f32_16x16x32_bf16(
                    af, bfr[n], acc[t][n], 0, 0, 0);
        }
    };

    // ---- barrier-free K-loop, DEPTH-deep prefetch ring (all static idx) ----
    if constexpr (MODE == 0) {
        constexpr int DEPTH = 4;           // 4 sets x 4t x short8 = 64 VGPR
        short8 a[DEPTH][T_];
#pragma unroll
        for (int p = 0; p < DEPTH; ++p) loadAb(p, a[p]);
#pragma unroll
        for (int s = 0; s < NS; ++s) {
            stepB(a[s % DEPTH], s);
            if (s + DEPTH < NS) loadAb(s + DEPTH, a[s % DEPTH]);
        }
    } else {
        constexpr int DEPTH = 6;           // 6 sets x 4t x uint2 = 48 VGPR
        uint2 a[DEPTH][T_];
#pragma unroll
        for (int p = 0; p < DEPTH; ++p) loadAu(p, a[p]);
#pragma unroll
        for (int s = 0; s < NS; ++s) {
            stepU(a[s % DEPTH], s);
            if (s + DEPTH < NS) loadAu(s + DEPTH, a[s % DEPTH]);
        }
    }

    __syncthreads();   // B panel dead; epilogue LDS aliases it

    // ---- epilogue: thread-local LIF t-scan + LDS repack + coalesced stores ----
    // C/D map: col = l&15 (+n*16), row = (l>>4)*4 + j (+ w*16)
    if constexpr (MODE == 2) {
        float* fl = (float*)smem;              // [64][68] f32, padded
        float v[4][4];
#pragma unroll
        for (int n = 0; n < 4; ++n)
#pragma unroll
            for (int j = 0; j < 4; ++j) v[n][j] = 0.f;
#pragma unroll
        for (int t = 0; t < T_; ++t) {
#pragma unroll
            for (int n = 0; n < 4; ++n)
#pragma unroll
                for (int j = 0; j < 4; ++j) {
                    v[n][j] = 0.5f * (v[n][j] + acc[t][n][j]);
                    const bool sp = (v[n][j] >= 1.f);
                    if (sp) v[n][j] = 0.f;
                    fl[(w * 16 + (l >> 4) * 4 + j) * 68 + n * 16 + (l & 15)] =
                        sp ? 1.f : 0.f;
                }
            __syncthreads();
            const int r  = tid >> 2;
            const int cb = (tid & 3) * 16;
            float* op = (float*)Out +
                ((size_t)(t * BNTOT + row0 + r)) * NOUT + col0 + cb;
#pragma unroll
            for (int k = 0; k < 4; ++k)
                *(float4*)(op + k * 4) = *(const float4*)&fl[r * 68 + cb + k * 4];
            __syncthreads();
        }
    } else {
        char* el = smem;   // [4t][4w][8cg][16r][8c] = 16KB
        float v[4][4];
#pragma unroll
        for (int n = 0; n < 4; ++n)
#pragma unroll
            for (int j = 0; j < 4; ++j) v[n][j] = 0.f;
#pragma unroll
        for (int t = 0; t < T_; ++t)
#pragma unroll
            for (int n = 0; n < 4; ++n)
#pragma unroll
                for (int j = 0; j < 4; ++j) {
                    v[n][j] = 0.5f * (v[n][j] + acc[t][n][j]);
                    const bool sp = (v[n][j] >= 1.f);
                    if (sp) v[n][j] = 0.f;
                    el[t * 4096 + w * 1024 + (n * 2 + ((l & 15) >> 3)) * 128 +
                       ((l >> 4) * 4 + j) * 8 + (l & 7)] =
                        (MODE == 0) ? (sp ? 1 : 0) : (sp ? 0 : 0xFF);
                }
        __syncthreads();
        // 64 consecutive bytes per thread -> 4 coalesced uint4 stores
        const int lin = tid * 64;
        const int t  = lin >> 12;
        const int w2 = (lin >> 10) & 3;
        const int cg = (lin >> 7) & 7;
        const size_t gb = ((size_t)(t * (BNTOT / 16) + (row0 >> 4) + w2) *
                          (NOUT / 8) + (col0 >> 3) + cg) * 128 + (lin & 127);
#pragma unroll
        for (int k = 0; k < 4; ++k) {
            uint4 m = *(const uint4*)(el + lin + k * 16);
            if constexpr (MODE == 1) {
                const uint4 h = *(const uint4*)((const uint8_t*)Av + gb + k * 16);
                m.x &= h.x; m.y &= h.y; m.z &= h.z; m.w &= h.w;
            }
            *(uint4*)((uint8_t*)Out + gb + k * 16) = m;
        }
    }
}

extern "C" void kernel_launch(void* const* d_in, const int* in_sizes, int n_in,
                              void* d_out, int out_size, void* d_ws, size_t ws_size,
                              hipStream_t stream)
{
    const float* x     = (const float*)d_in[0];  // [4,32,1024,256]
    const float* w_in  = (const float*)d_in[1];  // [512,256]
    const float* w_h   = (const float*)d_in[2];  // [2,512,512]
    const float* w_out = (const float*)d_in[3];  // [256,512]

    // xbf (tiled bf16 x, 67MB) = d_out[0:67MB] (dead before L4 writes out)
    // hA u8 = d_ws[0:67.1MB), hB u8 = d_ws[67.1:134.2MB)
    ushort*  xbf = (ushort*)d_out;
    uint8_t* hA  = (uint8_t*)d_ws;
    uint8_t* hB  = hA + (size_t)T_ * BNTOT * 512;
    float*   out = (float*)d_out;

    cvt_tiled<<<16384, 256, 0, stream>>>(x, xbf);

    lif_mfma<0, 256, 512><<<4096, 256, 0, stream>>>(xbf, w_in, hA);
    lif_mfma<1, 512, 512><<<4096, 256, 0, stream>>>(hA, w_h, hB);
    lif_mfma<1, 512, 512><<<4096, 256, 0, stream>>>(hB, w_h + 512 * 512, hA);
    lif_mfma<2, 512, 256><<<2048, 256, 0, stream>>>(hA, w_out, out);
}